// Round 6
// baseline (23325.005 us; speedup 1.0000x reference)
//
#include <hip/hip_runtime.h>

// ---------------------------------------------------------------------------
// FocusModel: embed -> bidir LSTM (E=512->HE=512) -> bidir LSTM (1024->512)
//          -> decoder LSTM (HD=1024, one-hot argmax feedback) -> softmax/loss
// R9: R8 proved barrier-arrival contention is NOT the cost (distributed
// barrier == single-line barrier == 80 us/step). Remaining suspect: the
// agent-scope RELEASE at every arrival lowers to buffer_wbl2 (full L2
// writeback walk) -> 256 L2 flushes per decoder step. R9 removes ALL cache
// maintenance:
//   - every cross-block-visible store is a RELAXED AGENT atomic store
//     (sc1 write-through to LLC: h rings, hseq, hdec, idx, init) -- the same
//     mechanism whose load side already worked in R6/R8.
//   - barrier arrival = inline-asm s_waitcnt vmcnt(0) (stores acked at LLC)
//     + RELAXED fetch_add. No release/acquire/wbl2/inv anywhere.
//   - readers: ring-fresh plain loads (R6-proven) or relaxed atomic loads
//     for reused addresses (hdec, idx).
// Topology/math identical to R8 (128 blocks x 64 thr, verified numerics).
// ---------------------------------------------------------------------------

typedef __bf16 bf16_t;
typedef __bf16 bf16x8 __attribute__((ext_vector_type(8)));
typedef __bf16 bf16x4 __attribute__((ext_vector_type(4)));
typedef float  f32x4  __attribute__((ext_vector_type(4)));

#define NB 128
#define LQ 160
#define EE 512
#define HE 512
#define HD 1024
#define TT 128

__device__ __forceinline__ f32x4 mfma16(bf16x8 a, bf16x8 b, f32x4 c) {
    return __builtin_amdgcn_mfma_f32_16x16x32_bf16(a, b, c, 0, 0, 0);
}
__device__ __forceinline__ bf16x8 ldf(const bf16_t* p) { return *(const bf16x8*)p; }
__device__ __forceinline__ float sigf(float x) { return 1.0f / (1.0f + __expf(-x)); }

// write-through (sc1) stores: visible at the coherent point once vmcnt acks.
__device__ __forceinline__ void stb16(bf16_t* p, bf16_t v) {
    union { bf16_t b; unsigned short u; } cv;
    cv.b = v;
    __hip_atomic_store((unsigned short*)p, cv.u, __ATOMIC_RELAXED,
                       __HIP_MEMORY_SCOPE_AGENT);
}
__device__ __forceinline__ void stf32(float* p, float v) {
    union { float f; unsigned u; } cv;
    cv.f = v;
    __hip_atomic_store((unsigned*)p, cv.u, __ATOMIC_RELAXED,
                       __HIP_MEMORY_SCOPE_AGENT);
}

// 8 f32 -> bf16x8 (RNE, same numerics as k_cvt).
__device__ __forceinline__ bf16x8 cvt8(const float* p) {
    float4 f0 = ((const float4*)p)[0];
    float4 f1 = ((const float4*)p)[1];
    bf16x8 a;
    a[0] = (bf16_t)f0.x; a[1] = (bf16_t)f0.y; a[2] = (bf16_t)f0.z; a[3] = (bf16_t)f0.w;
    a[4] = (bf16_t)f1.x; a[5] = (bf16_t)f1.y; a[6] = (bf16_t)f1.z; a[7] = (bf16_t)f1.w;
    return a;
}

// ---------------------------------------------------------------------------
// Distributed grid barrier, generation-free, NO cache maintenance.
// Arrival: s_waitcnt vmcnt(0) (this wave's write-through stores acked at the
// coherent point) + RELAXED fetch_add on line (blockIdx&15).
// Wait: lanes 0-15 poll the 16 lines (relaxed agent loads), butterfly-sum.
// ---------------------------------------------------------------------------
#define BAR_STRIDE 256  // u32s per barrier instance (16 lines x 16 u32)
__device__ __forceinline__ void gbar(unsigned* __restrict__ bars, int& bidx,
                                     unsigned nblk) {
    unsigned* lines = bars + (size_t)bidx * BAR_STRIDE;
    asm volatile("s_waitcnt vmcnt(0)" ::: "memory");
    __syncthreads();
    if (threadIdx.x == 0)
        __hip_atomic_fetch_add(lines + (blockIdx.x & 15) * 16, 1u,
                               __ATOMIC_RELAXED, __HIP_MEMORY_SCOPE_AGENT);
    if (threadIdx.x < 16) {
        for (;;) {
            unsigned s = __hip_atomic_load(lines + threadIdx.x * 16,
                                           __ATOMIC_RELAXED,
                                           __HIP_MEMORY_SCOPE_AGENT);
            s += __shfl_xor(s, 1);
            s += __shfl_xor(s, 2);
            s += __shfl_xor(s, 4);
            s += __shfl_xor(s, 8);
            if (s >= nblk) break;
            __builtin_amdgcn_s_sleep(4);
        }
    }
    __syncthreads();
    ++bidx;
}

// f32 -> bf16 bulk convert (n4 = n/4, all sizes divisible by 4).
__global__ __launch_bounds__(256) void k_cvt(const float* __restrict__ src,
                                             bf16_t* __restrict__ dst, int n4) {
    int i = blockIdx.x * 256 + threadIdx.x;
    if (i < n4) {
        float4 v = ((const float4*)src)[i];
        bf16x4 o;
        o[0] = (bf16_t)v.x; o[1] = (bf16_t)v.y; o[2] = (bf16_t)v.z; o[3] = (bf16_t)v.w;
        ((bf16x4*)dst)[i] = o;
    }
}

// ---------------------------------------------------------------------------
// Chunked input projection, layer 0. Rows m = (s-s0)*128 + b; per-direction
// source timestep t = d ? L-1-s : s; A-row = embed[ids[b][t]] (f32 gather,
// converted in-register). grid (CH*2, 32, 2), block 64.
// ---------------------------------------------------------------------------
__global__ __launch_bounds__(64) void k_xg0c(const int* __restrict__ ids,
                                             const float* __restrict__ embed,
                                             const bf16_t* __restrict__ wih,
                                             bf16_t* __restrict__ xgc,
                                             int s0) {
    const int lane = threadIdx.x;
    const int l15 = lane & 15, quad = lane >> 4;
    const int m0 = blockIdx.x * 64;
    const int n0 = blockIdx.y * 64;
    const int d  = blockIdx.z;
    const bf16_t* Wd = wih + (size_t)d * 2048 * 512;

    const float* arow[4];
#pragma unroll
    for (int mi = 0; mi < 4; ++mi) {
        int m = m0 + mi * 16 + l15;
        int b = m & 127, s = s0 + (m >> 7);
        int t = d ? (LQ - 1 - s) : s;
        int id = ids[b * LQ + t];
        arow[mi] = embed + (size_t)id * EE;
    }
    const bf16_t* brow[4];
#pragma unroll
    for (int ni = 0; ni < 4; ++ni) brow[ni] = Wd + (size_t)(n0 + ni * 16 + l15) * 512;

    f32x4 acc[4][4] = {};
    for (int kb = 0; kb < 512; kb += 32) {
        bf16x8 af[4], bfr[4];
#pragma unroll
        for (int mi = 0; mi < 4; ++mi) af[mi] = cvt8(arow[mi] + kb + quad * 8);
#pragma unroll
        for (int ni = 0; ni < 4; ++ni) bfr[ni] = ldf(brow[ni] + kb + quad * 8);
#pragma unroll
        for (int mi = 0; mi < 4; ++mi)
#pragma unroll
            for (int ni = 0; ni < 4; ++ni)
                acc[mi][ni] = mfma16(af[mi], bfr[ni], acc[mi][ni]);
    }
#pragma unroll
    for (int mi = 0; mi < 4; ++mi)
#pragma unroll
        for (int ni = 0; ni < 4; ++ni)
#pragma unroll
            for (int r = 0; r < 4; ++r) {
                int m = m0 + mi * 16 + quad * 4 + r;
                int n = n0 + ni * 16 + l15;
                xgc[(size_t)m * 4096 + d * 2048 + n] = (bf16_t)acc[mi][ni][r];
            }
}

// Chunked input projection, layer 1: A-row = h1ring[1+t][b] (1024 wide), K=1024.
__global__ __launch_bounds__(64) void k_xg1c(const bf16_t* __restrict__ h1,
                                             const bf16_t* __restrict__ wih,
                                             bf16_t* __restrict__ xgc,
                                             int s0) {
    const int lane = threadIdx.x;
    const int l15 = lane & 15, quad = lane >> 4;
    const int m0 = blockIdx.x * 64;
    const int n0 = blockIdx.y * 64;
    const int d  = blockIdx.z;
    const bf16_t* Wd = wih + (size_t)d * 2048 * 1024;

    const bf16_t* arow[4];
#pragma unroll
    for (int mi = 0; mi < 4; ++mi) {
        int m = m0 + mi * 16 + l15;
        int b = m & 127, s = s0 + (m >> 7);
        int t = d ? (LQ - 1 - s) : s;
        arow[mi] = h1 + ((size_t)(1 + t) * NB + b) * 1024;
    }
    const bf16_t* brow[4];
#pragma unroll
    for (int ni = 0; ni < 4; ++ni) brow[ni] = Wd + (size_t)(n0 + ni * 16 + l15) * 1024;

    f32x4 acc[4][4] = {};
    for (int kb = 0; kb < 1024; kb += 32) {
        bf16x8 af[4], bfr[4];
#pragma unroll
        for (int mi = 0; mi < 4; ++mi) af[mi] = ldf(arow[mi] + kb + quad * 8);
#pragma unroll
        for (int ni = 0; ni < 4; ++ni) bfr[ni] = ldf(brow[ni] + kb + quad * 8);
#pragma unroll
        for (int mi = 0; mi < 4; ++mi)
#pragma unroll
            for (int ni = 0; ni < 4; ++ni)
                acc[mi][ni] = mfma16(af[mi], bfr[ni], acc[mi][ni]);
    }
#pragma unroll
    for (int mi = 0; mi < 4; ++mi)
#pragma unroll
        for (int ni = 0; ni < 4; ++ni)
#pragma unroll
            for (int r = 0; r < 4; ++r) {
                int m = m0 + mi * 16 + quad * 4 + r;
                int n = n0 + ni * 16 + l15;
                xgc[(size_t)m * 4096 + d * 2048 + n] = (bf16_t)acc[mi][ni][r];
            }
}

// ---------------------------------------------------------------------------
// Persistent encoder chunk. 128 blocks x 64 thr; block bi -> m-block (bi&1),
// col-block ((bi>>1)&31), dir (bi>>6). Recurrent h read/written directly in
// the per-timestep ring hring[1+t][b][d*512+c] (slots 0, LQ+1 zeroed).
// h writes are write-through (stb16); reads are plain (ring-fresh lines).
// Cell state in registers across the chunk; persisted to cst between chunks.
// ---------------------------------------------------------------------------
__global__ __launch_bounds__(64) void k_enc_chunk(bf16_t* __restrict__ hring,
                                                  const bf16_t* __restrict__ whh,
                                                  const float* __restrict__ bias,
                                                  const bf16_t* __restrict__ xgc,
                                                  float* __restrict__ cst,
                                                  unsigned* __restrict__ bars,
                                                  int s0, int nsteps) {
    const int lane = threadIdx.x;
    const int l15 = lane & 15, quad = lane >> 4;
    const int bi = blockIdx.x;
    const int m0 = (bi & 1) * 64;
    const int c0 = ((bi >> 1) & 31) * 16;
    const int d  = bi >> 6;
    int bidx = 0;

    const bf16_t* Wd = whh + (size_t)d * 2048 * 512;
    const bf16_t* brow[4];
#pragma unroll
    for (int g4 = 0; g4 < 4; ++g4) brow[g4] = Wd + (size_t)(g4 * 512 + c0 + l15) * 512;
    const int c = c0 + l15;
    float bv[4];
#pragma unroll
    for (int g4 = 0; g4 < 4; ++g4) bv[g4] = bias[d * 2048 + g4 * 512 + c];
    size_t aoff[4];
#pragma unroll
    for (int mi = 0; mi < 4; ++mi) aoff[mi] = (size_t)(m0 + mi * 16 + l15) * 1024;

    // cell state in registers (block ownership constant across steps)
    float creg[4][4];
#pragma unroll
    for (int mi = 0; mi < 4; ++mi)
#pragma unroll
        for (int r = 0; r < 4; ++r) {
            int m = m0 + mi * 16 + quad * 4 + r;
            creg[mi][r] = cst[((size_t)d * NB + m) * 512 + c];
        }

    for (int s = s0; s < s0 + nsteps; ++s) {
        const int t     = d ? (LQ - 1 - s) : s;
        const int tprev = d ? (LQ - s)     : (s - 1);
        const bf16_t* abase = hring + ((size_t)(1 + tprev) * NB) * 1024 + (size_t)d * 512;

        f32x4 acc[4][4] = {};  // [mi][gate]
        for (int kb = 0; kb < 512; kb += 32) {
            bf16x8 af[4], bfr[4];
#pragma unroll
            for (int mi = 0; mi < 4; ++mi) af[mi] = ldf(abase + aoff[mi] + kb + quad * 8);
#pragma unroll
            for (int g4 = 0; g4 < 4; ++g4) bfr[g4] = ldf(brow[g4] + kb + quad * 8);
#pragma unroll
            for (int mi = 0; mi < 4; ++mi)
#pragma unroll
                for (int g4 = 0; g4 < 4; ++g4)
                    acc[mi][g4] = mfma16(af[mi], bfr[g4], acc[mi][g4]);
        }

        bf16_t* wbase = hring + ((size_t)(1 + t) * NB) * 1024 + (size_t)d * 512;
#pragma unroll
        for (int mi = 0; mi < 4; ++mi)
#pragma unroll
            for (int r = 0; r < 4; ++r) {
                int m = m0 + mi * 16 + quad * 4 + r;
                size_t xoff = ((size_t)(s - s0) * NB + m) * 4096 + (size_t)d * 2048;
                float gi = acc[mi][0][r] + (float)xgc[xoff + 0 * 512 + c] + bv[0];
                float gf = acc[mi][1][r] + (float)xgc[xoff + 1 * 512 + c] + bv[1];
                float gg = acc[mi][2][r] + (float)xgc[xoff + 2 * 512 + c] + bv[2];
                float go = acc[mi][3][r] + (float)xgc[xoff + 3 * 512 + c] + bv[3];
                float cn = sigf(gf) * creg[mi][r] + sigf(gi) * tanhf(gg);
                float hn = sigf(go) * tanhf(cn);
                creg[mi][r] = cn;
                stb16(wbase + (size_t)m * 1024 + c, (bf16_t)hn);
            }
        if (s + 1 < s0 + nsteps) gbar(bars, bidx, 128);
    }

#pragma unroll
    for (int mi = 0; mi < 4; ++mi)
#pragma unroll
        for (int r = 0; r < 4; ++r) {
            int m = m0 + mi * 16 + quad * 4 + r;
            cst[((size_t)d * NB + m) * 512 + c] = creg[mi][r];
        }
}

// ---------------------------------------------------------------------------
// Persistent decoder: init + 160 steps, 128 blocks x 64 thr.
// Phase A: gate GEMM (h from ring hseq[t], writes hseq[t+1] = h + enc[t+1],
//   write-through) + cell math (cells in regs); hdec (f32, write-through).
// Phase B: block bi = batch b; lane n computes tags n and n+64; hdec row
//   staged to LDS via atomic u32 loads (lane-stride-1, conflict-free);
//   shuffle softmax / first-max argmax / in-register loss.
// ---------------------------------------------------------------------------
__global__ __launch_bounds__(64) void k_dec_persist(const bf16_t* __restrict__ encb,
                                                    const bf16_t* __restrict__ whh,
                                                    const float* __restrict__ bias,
                                                    const float* __restrict__ wih,
                                                    const float* __restrict__ out_w,
                                                    const float* __restrict__ out_b,
                                                    const int* __restrict__ tags,
                                                    bf16_t* __restrict__ hseq,
                                                    float* __restrict__ hdec,
                                                    int* __restrict__ idx,
                                                    unsigned* __restrict__ bars,
                                                    float* __restrict__ prob_out,
                                                    float* __restrict__ loss_out) {
    const int lane = threadIdx.x;
    const int bi = blockIdx.x;
    const int l15 = lane & 15, quad = lane >> 4;
    const int m0 = (bi & 1) * 64;
    const int c0 = (bi >> 1) * 16;
    const int c = c0 + l15;
    int bidx = 0;
    __shared__ float hrow[HD];

    // ---- init own tile: hseq[0] = enc[0] (ring slot 1), c0 = [fb, fb] ----
    float creg[4][4];
#pragma unroll
    for (int mi = 0; mi < 4; ++mi)
#pragma unroll
        for (int r = 0; r < 4; ++r) {
            int m = m0 + mi * 16 + quad * 4 + r;
            creg[mi][r] = (float)encb[((size_t)1 * NB + m) * 1024 + 512 + (c & 511)];
            stb16(hseq + (size_t)m * HD + c, encb[((size_t)1 * NB + m) * 1024 + c]);
        }
    if (bi < 2)
        __hip_atomic_store(idx + bi * 64 + lane, -1, __ATOMIC_RELAXED,
                           __HIP_MEMORY_SCOPE_AGENT);

    // ---- hoisted gate-phase constants ----
    const bf16_t* brow[4];
#pragma unroll
    for (int g4 = 0; g4 < 4; ++g4) brow[g4] = whh + (size_t)(g4 * 1024 + c0 + l15) * 1024;
    float bv[4];
#pragma unroll
    for (int g4 = 0; g4 < 4; ++g4) bv[g4] = bias[g4 * 1024 + c];
    size_t aoff[4];
#pragma unroll
    for (int mi = 0; mi < 4; ++mi) aoff[mi] = (size_t)(m0 + mi * 16 + l15) * 1024;

    // ---- hoisted logits constants (block bi = batch b) ----
    const int b = bi;
    const float4* wl0 = (const float4*)(out_w + (size_t)lane * HD);
    const float4* wl1 = (const float4*)(out_w + (size_t)(lane + 64) * HD);
    const float ob0 = out_b[lane], ob1 = out_b[lane + 64];
    float loss_acc = 0.0f;

    gbar(bars, bidx, 128);

    for (int t = 0; t < LQ; ++t) {
        // ================= phase A: gates + cell =================
        const bf16_t* hin = hseq + (size_t)t * (NB * HD);

        // hoist idx reads (coherent-point loads, hidden under the GEMM)
        int idr[4][4];
#pragma unroll
        for (int mi = 0; mi < 4; ++mi)
#pragma unroll
            for (int r = 0; r < 4; ++r) {
                int m = m0 + mi * 16 + quad * 4 + r;
                idr[mi][r] = __hip_atomic_load(idx + m, __ATOMIC_RELAXED,
                                               __HIP_MEMORY_SCOPE_AGENT);
            }

        f32x4 acc[4][4] = {};
        for (int kb = 0; kb < 1024; kb += 32) {
            bf16x8 af[4], bfr[4];
#pragma unroll
            for (int mi = 0; mi < 4; ++mi) af[mi] = ldf(hin + aoff[mi] + kb + quad * 8);
#pragma unroll
            for (int g4 = 0; g4 < 4; ++g4) bfr[g4] = ldf(brow[g4] + kb + quad * 8);
#pragma unroll
            for (int mi = 0; mi < 4; ++mi)
#pragma unroll
                for (int g4 = 0; g4 < 4; ++g4)
                    acc[mi][g4] = mfma16(af[mi], bfr[g4], acc[mi][g4]);
        }

        bf16_t* wnext = hseq + (size_t)(t + 1) * (NB * HD);
#pragma unroll
        for (int mi = 0; mi < 4; ++mi)
#pragma unroll
            for (int r = 0; r < 4; ++r) {
                int m = m0 + mi * 16 + quad * 4 + r;
                int id = idr[mi][r];
                float gv[4];
#pragma unroll
                for (int g4 = 0; g4 < 4; ++g4) {
                    float wi = (id >= 0) ? wih[(size_t)(g4 * 1024 + c) * TT + id] : 0.0f;
                    gv[g4] = acc[mi][g4][r] + bv[g4] + wi;
                }
                float cn = sigf(gv[1]) * creg[mi][r] + sigf(gv[0]) * tanhf(gv[2]);
                float hn = sigf(gv[3]) * tanhf(cn);
                creg[mi][r] = cn;
                stf32(hdec + (size_t)m * HD + c, hn);
                if (t + 1 < LQ)
                    stb16(wnext + (size_t)m * HD + c,
                          (bf16_t)(hn + (float)encb[((size_t)(t + 2) * NB + m) * 1024 + c]));
            }
        gbar(bars, bidx, 128);

        // ================= phase B: logits / softmax / argmax / loss =======
        // stage hdec row b via coherent-point u32 loads, lane-stride-1
        const unsigned* hsrc = (const unsigned*)(hdec + (size_t)b * HD);
#pragma unroll
        for (int k = 0; k < 16; ++k) {
            unsigned v = __hip_atomic_load(hsrc + lane + k * 64, __ATOMIC_RELAXED,
                                           __HIP_MEMORY_SCOPE_AGENT);
            ((unsigned*)hrow)[lane + k * 64] = v;
        }
        __syncthreads();

        float a0 = ob0, a1 = ob1;
        for (int k = 0; k < HD / 4; ++k) {
            float4 h4 = ((const float4*)hrow)[k];
            float4 x0 = wl0[k];
            float4 x1 = wl1[k];
            a0 += h4.x * x0.x + h4.y * x0.y + h4.z * x0.z + h4.w * x0.w;
            a1 += h4.x * x1.x + h4.y * x1.y + h4.z * x1.z + h4.w * x1.w;
        }
        float mx = fmaxf(a0, a1);
#pragma unroll
        for (int off2 = 32; off2 > 0; off2 >>= 1) mx = fmaxf(mx, __shfl_xor(mx, off2));
        float sm = __expf(a0 - mx) + __expf(a1 - mx);
#pragma unroll
        for (int off2 = 32; off2 > 0; off2 >>= 1) sm += __shfl_xor(sm, off2);
        float lse = mx + logf(sm);
        size_t pbase = (size_t)b * (LQ * TT) + (size_t)t * TT;
        prob_out[pbase + lane] = __expf(a0 - lse);
        prob_out[pbase + lane + 64] = __expf(a1 - lse);

        // first-max argmax (smaller index wins ties)
        float bvv;
        int bix;
        if (a1 > a0) { bvv = a1; bix = lane + 64; } else { bvv = a0; bix = lane; }
#pragma unroll
        for (int off2 = 32; off2 > 0; off2 >>= 1) {
            float ov = __shfl_xor(bvv, off2);
            int oi = __shfl_xor(bix, off2);
            if (ov > bvv || (ov == bvv && oi < bix)) { bvv = ov; bix = oi; }
        }
        if (lane == 0)
            __hip_atomic_store(idx + b, bix, __ATOMIC_RELAXED,
                               __HIP_MEMORY_SCOPE_AGENT);

        int tg = tags[b * LQ + t];
        float l0 = __shfl(a0, tg & 63);
        float l1 = __shfl(a1, tg & 63);
        float lv = (tg >= 64) ? l1 : l0;
        if (lane == 0) loss_acc += -(lv - lse) * (1.0f / 128.0f);
        gbar(bars, bidx, 128);
    }
    if (lane == 0) atomicAdd(loss_out, loss_acc);
}

// ---------------------------------------------------------------------------
extern "C" void kernel_launch(void* const* d_in, const int* in_sizes, int n_in,
                              void* d_out, int out_size, void* d_ws, size_t ws_size,
                              hipStream_t stream) {
    (void)in_sizes; (void)n_in; (void)out_size;
    const int*   ids    = (const int*)d_in[0];
    const int*   tags   = (const int*)d_in[1];
    const float* embed  = (const float*)d_in[2];
    const float* e0_wih = (const float*)d_in[3];
    const float* e0_whh = (const float*)d_in[4];
    const float* e0_b   = (const float*)d_in[5];
    const float* e1_wih = (const float*)d_in[6];
    const float* e1_whh = (const float*)d_in[7];
    const float* e1_b   = (const float*)d_in[8];
    const float* d_wih  = (const float*)d_in[9];
    const float* d_whh  = (const float*)d_in[10];
    const float* d_b    = (const float*)d_in[11];
    const float* out_w  = (const float*)d_in[12];
    const float* out_b  = (const float*)d_in[13];
    float* prob = (float*)d_out;

    char* ws = (char*)d_ws;
    size_t off = 0;
    auto alloc = [&](size_t bytes) -> void* {
        void* p = ws + off;
        off += (bytes + 255) & ~(size_t)255;
        return p;
    };
    // bf16 weights (~28 MiB; embed stays f32, converted in-register in xg0):
    bf16_t* e0wihB = (bf16_t*)alloc((size_t)2 * 2048 * 512 * 2);
    bf16_t* e0whhB = (bf16_t*)alloc((size_t)2 * 2048 * 512 * 2);
    bf16_t* e1wihB = (bf16_t*)alloc((size_t)2 * 2048 * 1024 * 2);
    bf16_t* e1whhB = (bf16_t*)alloc((size_t)2 * 2048 * 512 * 2);
    bf16_t* dwhhB  = (bf16_t*)alloc((size_t)4096 * 1024 * 2);
    // per-timestep state rings (~125 MiB):
    bf16_t* h1    = (bf16_t*)alloc((size_t)(LQ + 2) * NB * 1024 * 2);  // enc0 ring
    bf16_t* encb  = (bf16_t*)alloc((size_t)(LQ + 2) * NB * 1024 * 2);  // enc1 ring
    bf16_t* hseqD = (bf16_t*)alloc((size_t)LQ * NB * HD * 2);          // decoder ring
    float*  cstE  = (float*)alloc((size_t)2 * 2 * NB * 512 * 4);       // [layer][dir][N][HE]
    float*  hdec  = (float*)alloc((size_t)NB * HD * 4);
    int*    idx   = (int*)alloc(NB * 4);
    // barrier sets: 1024 instances x 16 lines x 64 B = 1 MiB, pre-zeroed.
    unsigned* bars = (unsigned*)alloc((size_t)1024 * BAR_STRIDE * 4);
    size_t fixed_end = off;

    // Step-chunked input-projection gate buffer, sized from ws_size.
    static const int ch_opts[] = {40, 32, 20, 16, 10, 8, 5, 4, 2, 1};
    int CH = 1;
    for (int i = 0; i < 10; ++i) {
        size_t need = (size_t)ch_opts[i] * NB * 4096 * 2;
        if (fixed_end + need <= ws_size) { CH = ch_opts[i]; break; }
    }
    bf16_t* xgc = (bf16_t*)alloc((size_t)CH * NB * 4096 * 2);

    // ---- one-time weight conversion ----
    auto cvt = [&](const float* s, bf16_t* d, size_t n) {
        int n4 = (int)(n / 4);
        k_cvt<<<dim3((n4 + 255) / 256), 256, 0, stream>>>(s, d, n4);
    };
    cvt(e0_wih, e0wihB, (size_t)2 * 2048 * 512);
    cvt(e0_whh, e0whhB, (size_t)2 * 2048 * 512);
    cvt(e1_wih, e1wihB, (size_t)2 * 2048 * 1024);
    cvt(e1_whh, e1whhB, (size_t)2 * 2048 * 512);
    cvt(d_whh, dwhhB, (size_t)4096 * 1024);

    const size_t SLOT = (size_t)NB * 1024;  // ring slot elems
    hipMemsetAsync(h1, 0, SLOT * 2, stream);                            // slot 0
    hipMemsetAsync(h1 + (size_t)(LQ + 1) * SLOT, 0, SLOT * 2, stream);  // slot LQ+1
    hipMemsetAsync(encb, 0, SLOT * 2, stream);
    hipMemsetAsync(encb + (size_t)(LQ + 1) * SLOT, 0, SLOT * 2, stream);
    hipMemsetAsync(cstE, 0, (size_t)2 * 2 * NB * 512 * 4, stream);
    hipMemsetAsync(bars, 0, (size_t)1024 * BAR_STRIDE * 4, stream);
    hipMemsetAsync(prob + (size_t)NB * LQ * TT, 0, 4, stream);  // loss scalar

    // barrier-set regions: enc0 chunk cc -> sets [cc*CH ..], enc1 -> LQ + cc*CH,
    // decoder -> 2*LQ .. (needs 1 + 2*LQ = 321 sets; 1024 allocated)
    // ---- encoder layer 0 ----
    for (int cc = 0; cc < LQ / CH; ++cc) {
        int s0 = cc * CH;
        k_xg0c<<<dim3(CH * 2, 32, 2), 64, 0, stream>>>(ids, embed, e0wihB, xgc, s0);
        k_enc_chunk<<<dim3(128), 64, 0, stream>>>(h1, e0whhB, e0_b, xgc, cstE,
                                                  bars + (size_t)(cc * CH) * BAR_STRIDE,
                                                  s0, CH);
    }
    // ---- encoder layer 1 ----
    for (int cc = 0; cc < LQ / CH; ++cc) {
        int s0 = cc * CH;
        k_xg1c<<<dim3(CH * 2, 32, 2), 64, 0, stream>>>(h1, e1wihB, xgc, s0);
        k_enc_chunk<<<dim3(128), 64, 0, stream>>>(encb, e1whhB, e1_b, xgc,
                                                  cstE + (size_t)2 * NB * 512,
                                                  bars + (size_t)(LQ + cc * CH) * BAR_STRIDE,
                                                  s0, CH);
    }
    // ---- decoder (one persistent launch) ----
    k_dec_persist<<<dim3(128), 64, 0, stream>>>(encb, dwhhB, d_b, d_wih, out_w, out_b,
                                                tags, hseqD, hdec, idx,
                                                bars + (size_t)(2 * LQ) * BAR_STRIDE,
                                                prob, prob + (size_t)NB * LQ * TT);
}

// Round 7
// 16210.535 us; speedup vs baseline: 1.4389x; 1.4389x over previous
//
#include <hip/hip_runtime.h>

// ---------------------------------------------------------------------------
// FocusModel: embed -> bidir LSTM (E=512->HE=512) -> bidir LSTM (1024->512)
//          -> decoder LSTM (HD=1024, one-hot argmax feedback) -> softmax/loss
// R10: R6/R8/R9 proved the ~80us/step decoder cost is insensitive to barrier
// implementation. Attack the structure instead:
//   - decoder = TWO independent 64-block pipelines (batch halves); ONE
//     barrier per step (post-gates); idx feedback via per-step idx_ring with
//     sentinel polling in the next step's epilogue; hdec = 2-slot ring
//     (atomic readers -> slot reuse safe under max-skew-1).
//   - gate GEMM K=1024 split across 2 waves/block (half latency chain, 2
//     waves/CU); partials combined via padded LDS.
//   - depth-2 register prefetch in all K-loops.
//   - wihT transpose for coalesced one-hot gather.
//   - encoder barrier groups = true dependency set (32 blocks: same m-block
//     + direction).
// Numerics identical to the verified R3..R9 chain.
// ---------------------------------------------------------------------------

typedef __bf16 bf16_t;
typedef __bf16 bf16x8 __attribute__((ext_vector_type(8)));
typedef __bf16 bf16x4 __attribute__((ext_vector_type(4)));
typedef float  f32x4  __attribute__((ext_vector_type(4)));

#define NB 128
#define LQ 160
#define EE 512
#define HE 512
#define HD 1024
#define TT 128

__device__ __forceinline__ f32x4 mfma16(bf16x8 a, bf16x8 b, f32x4 c) {
    return __builtin_amdgcn_mfma_f32_16x16x32_bf16(a, b, c, 0, 0, 0);
}
__device__ __forceinline__ bf16x8 ldf(const bf16_t* p) { return *(const bf16x8*)p; }
__device__ __forceinline__ float sigf(float x) { return 1.0f / (1.0f + __expf(-x)); }

// write-through (agent-scope) stores: visible at the coherent point.
__device__ __forceinline__ void stb16(bf16_t* p, bf16_t v) {
    union { bf16_t b; unsigned short u; } cv;
    cv.b = v;
    __hip_atomic_store((unsigned short*)p, cv.u, __ATOMIC_RELAXED,
                       __HIP_MEMORY_SCOPE_AGENT);
}
__device__ __forceinline__ void stf32(float* p, float v) {
    union { float f; unsigned u; } cv;
    cv.f = v;
    __hip_atomic_store((unsigned*)p, cv.u, __ATOMIC_RELAXED,
                       __HIP_MEMORY_SCOPE_AGENT);
}

// 8 f32 -> bf16x8 (RNE).
__device__ __forceinline__ bf16x8 cvt8(const float* p) {
    float4 f0 = ((const float4*)p)[0];
    float4 f1 = ((const float4*)p)[1];
    bf16x8 a;
    a[0] = (bf16_t)f0.x; a[1] = (bf16_t)f0.y; a[2] = (bf16_t)f0.z; a[3] = (bf16_t)f0.w;
    a[4] = (bf16_t)f1.x; a[5] = (bf16_t)f1.y; a[6] = (bf16_t)f1.z; a[7] = (bf16_t)f1.w;
    return a;
}

// ---------------------------------------------------------------------------
// Distributed group barrier (generation-free, no cache maintenance).
// lines = this barrier instance (16 cache lines, pre-zeroed). Arrival:
// vmcnt(0) drain + RELAXED fetch_add on line ((blockIdx>>1)&15). Wait:
// lanes 0-15 poll the 16 lines, butterfly-sum >= nblk.
// ---------------------------------------------------------------------------
#define BAR_STRIDE 256  // u32s per instance (16 lines x 16 u32 = 1 KiB)
__device__ __forceinline__ void gbar(unsigned* __restrict__ lines, unsigned nblk) {
    asm volatile("s_waitcnt vmcnt(0)" ::: "memory");
    __syncthreads();
    if (threadIdx.x == 0)
        __hip_atomic_fetch_add(lines + ((blockIdx.x >> 1) & 15) * 16, 1u,
                               __ATOMIC_RELAXED, __HIP_MEMORY_SCOPE_AGENT);
    if (threadIdx.x < 16) {
        for (;;) {
            unsigned s = __hip_atomic_load(lines + threadIdx.x * 16,
                                           __ATOMIC_RELAXED,
                                           __HIP_MEMORY_SCOPE_AGENT);
            s += __shfl_xor(s, 1);
            s += __shfl_xor(s, 2);
            s += __shfl_xor(s, 4);
            s += __shfl_xor(s, 8);
            if (s >= nblk) break;
            __builtin_amdgcn_s_sleep(2);
        }
    }
    __syncthreads();
}

// f32 -> bf16 bulk convert.
__global__ __launch_bounds__(256) void k_cvt(const float* __restrict__ src,
                                             bf16_t* __restrict__ dst, int n4) {
    int i = blockIdx.x * 256 + threadIdx.x;
    if (i < n4) {
        float4 v = ((const float4*)src)[i];
        bf16x4 o;
        o[0] = (bf16_t)v.x; o[1] = (bf16_t)v.y; o[2] = (bf16_t)v.z; o[3] = (bf16_t)v.w;
        ((bf16x4*)dst)[i] = o;
    }
}

// dec_wih [4096][128] -> wihT [128][4096] (f32), for coalesced id-gather.
__global__ __launch_bounds__(256) void k_tw(const float* __restrict__ w,
                                            float* __restrict__ wt) {
    int i = blockIdx.x * 256 + threadIdx.x;
    if (i < 4096 * 128) {
        int r = i >> 7, c2 = i & 127;
        wt[(size_t)c2 * 4096 + r] = w[i];
    }
}

// ---------------------------------------------------------------------------
// Chunked input projection, layer 0 (embed gather fused, f32->bf16 in-reg).
// ---------------------------------------------------------------------------
__global__ __launch_bounds__(64) void k_xg0c(const int* __restrict__ ids,
                                             const float* __restrict__ embed,
                                             const bf16_t* __restrict__ wih,
                                             bf16_t* __restrict__ xgc,
                                             int s0) {
    const int lane = threadIdx.x;
    const int l15 = lane & 15, quad = lane >> 4;
    const int m0 = blockIdx.x * 64;
    const int n0 = blockIdx.y * 64;
    const int d  = blockIdx.z;
    const bf16_t* Wd = wih + (size_t)d * 2048 * 512;

    const float* arow[4];
#pragma unroll
    for (int mi = 0; mi < 4; ++mi) {
        int m = m0 + mi * 16 + l15;
        int b = m & 127, s = s0 + (m >> 7);
        int t = d ? (LQ - 1 - s) : s;
        int id = ids[b * LQ + t];
        arow[mi] = embed + (size_t)id * EE;
    }
    const bf16_t* brow[4];
#pragma unroll
    for (int ni = 0; ni < 4; ++ni) brow[ni] = Wd + (size_t)(n0 + ni * 16 + l15) * 512;

    f32x4 acc[4][4] = {};
    for (int kb = 0; kb < 512; kb += 32) {
        bf16x8 af[4], bfr[4];
#pragma unroll
        for (int mi = 0; mi < 4; ++mi) af[mi] = cvt8(arow[mi] + kb + quad * 8);
#pragma unroll
        for (int ni = 0; ni < 4; ++ni) bfr[ni] = ldf(brow[ni] + kb + quad * 8);
#pragma unroll
        for (int mi = 0; mi < 4; ++mi)
#pragma unroll
            for (int ni = 0; ni < 4; ++ni)
                acc[mi][ni] = mfma16(af[mi], bfr[ni], acc[mi][ni]);
    }
#pragma unroll
    for (int mi = 0; mi < 4; ++mi)
#pragma unroll
        for (int ni = 0; ni < 4; ++ni)
#pragma unroll
            for (int r = 0; r < 4; ++r) {
                int m = m0 + mi * 16 + quad * 4 + r;
                int n = n0 + ni * 16 + l15;
                xgc[(size_t)m * 4096 + d * 2048 + n] = (bf16_t)acc[mi][ni][r];
            }
}

// Chunked input projection, layer 1: A-row = h1ring[1+t][b] (1024 wide).
__global__ __launch_bounds__(64) void k_xg1c(const bf16_t* __restrict__ h1,
                                             const bf16_t* __restrict__ wih,
                                             bf16_t* __restrict__ xgc,
                                             int s0) {
    const int lane = threadIdx.x;
    const int l15 = lane & 15, quad = lane >> 4;
    const int m0 = blockIdx.x * 64;
    const int n0 = blockIdx.y * 64;
    const int d  = blockIdx.z;
    const bf16_t* Wd = wih + (size_t)d * 2048 * 1024;

    const bf16_t* arow[4];
#pragma unroll
    for (int mi = 0; mi < 4; ++mi) {
        int m = m0 + mi * 16 + l15;
        int b = m & 127, s = s0 + (m >> 7);
        int t = d ? (LQ - 1 - s) : s;
        arow[mi] = h1 + ((size_t)(1 + t) * NB + b) * 1024;
    }
    const bf16_t* brow[4];
#pragma unroll
    for (int ni = 0; ni < 4; ++ni) brow[ni] = Wd + (size_t)(n0 + ni * 16 + l15) * 1024;

    f32x4 acc[4][4] = {};
    for (int kb = 0; kb < 1024; kb += 32) {
        bf16x8 af[4], bfr[4];
#pragma unroll
        for (int mi = 0; mi < 4; ++mi) af[mi] = ldf(arow[mi] + kb + quad * 8);
#pragma unroll
        for (int ni = 0; ni < 4; ++ni) bfr[ni] = ldf(brow[ni] + kb + quad * 8);
#pragma unroll
        for (int mi = 0; mi < 4; ++mi)
#pragma unroll
            for (int ni = 0; ni < 4; ++ni)
                acc[mi][ni] = mfma16(af[mi], bfr[ni], acc[mi][ni]);
    }
#pragma unroll
    for (int mi = 0; mi < 4; ++mi)
#pragma unroll
        for (int ni = 0; ni < 4; ++ni)
#pragma unroll
            for (int r = 0; r < 4; ++r) {
                int m = m0 + mi * 16 + quad * 4 + r;
                int n = n0 + ni * 16 + l15;
                xgc[(size_t)m * 4096 + d * 2048 + n] = (bf16_t)acc[mi][ni][r];
            }
}

// ---------------------------------------------------------------------------
// Persistent encoder chunk. 128 blocks x 64 thr; block bi -> m-block (bi&1),
// col-block ((bi>>1)&31), dir (bi>>6). Barrier group = (m-block, dir): the
// exact reader->writer dependency set (32 blocks). Depth-2 reg prefetch.
// ---------------------------------------------------------------------------
__global__ __launch_bounds__(64) void k_enc_chunk(bf16_t* __restrict__ hring,
                                                  const bf16_t* __restrict__ whh,
                                                  const float* __restrict__ bias,
                                                  const bf16_t* __restrict__ xgc,
                                                  float* __restrict__ cst,
                                                  unsigned* __restrict__ bars,
                                                  int s0, int nsteps) {
    const int lane = threadIdx.x;
    const int l15 = lane & 15, quad = lane >> 4;
    const int bi = blockIdx.x;
    const int m0 = (bi & 1) * 64;
    const int c0 = ((bi >> 1) & 31) * 16;
    const int d  = bi >> 6;
    const int grp = (bi & 1) | ((bi >> 6) << 1);

    const bf16_t* Wd = whh + (size_t)d * 2048 * 512;
    const bf16_t* brow[4];
#pragma unroll
    for (int g4 = 0; g4 < 4; ++g4) brow[g4] = Wd + (size_t)(g4 * 512 + c0 + l15) * 512;
    const int c = c0 + l15;
    float bv[4];
#pragma unroll
    for (int g4 = 0; g4 < 4; ++g4) bv[g4] = bias[d * 2048 + g4 * 512 + c];
    size_t aoff[4];
#pragma unroll
    for (int mi = 0; mi < 4; ++mi) aoff[mi] = (size_t)(m0 + mi * 16 + l15) * 1024;

    float creg[4][4];
#pragma unroll
    for (int mi = 0; mi < 4; ++mi)
#pragma unroll
        for (int r = 0; r < 4; ++r) {
            int m = m0 + mi * 16 + quad * 4 + r;
            creg[mi][r] = cst[((size_t)d * NB + m) * 512 + c];
        }

    for (int s = s0; s < s0 + nsteps; ++s) {
        const int t     = d ? (LQ - 1 - s) : s;
        const int tprev = d ? (LQ - s)     : (s - 1);
        const bf16_t* abase = hring + ((size_t)(1 + tprev) * NB) * 1024 + (size_t)d * 512;

        f32x4 acc[4][4] = {};
        bf16x8 a0[4], b0[4], a1[4], b1[4];
        auto LD = [&](bf16x8* A, bf16x8* B, int kb) {
#pragma unroll
            for (int mi = 0; mi < 4; ++mi) A[mi] = ldf(abase + aoff[mi] + kb + quad * 8);
#pragma unroll
            for (int g4 = 0; g4 < 4; ++g4) B[g4] = ldf(brow[g4] + kb + quad * 8);
        };
        auto MM = [&](bf16x8* A, bf16x8* B) {
#pragma unroll
            for (int mi = 0; mi < 4; ++mi)
#pragma unroll
                for (int g4 = 0; g4 < 4; ++g4)
                    acc[mi][g4] = mfma16(A[mi], B[g4], acc[mi][g4]);
        };
        LD(a0, b0, 0);
        for (int it = 0; it < 7; ++it) {
            int kb = it * 64;
            LD(a1, b1, kb + 32); MM(a0, b0);
            LD(a0, b0, kb + 64); MM(a1, b1);
        }
        LD(a1, b1, 480); MM(a0, b0); MM(a1, b1);

        bf16_t* wbase = hring + ((size_t)(1 + t) * NB) * 1024 + (size_t)d * 512;
#pragma unroll
        for (int mi = 0; mi < 4; ++mi)
#pragma unroll
            for (int r = 0; r < 4; ++r) {
                int m = m0 + mi * 16 + quad * 4 + r;
                size_t xoff = ((size_t)(s - s0) * NB + m) * 4096 + (size_t)d * 2048;
                float gi = acc[mi][0][r] + (float)xgc[xoff + 0 * 512 + c] + bv[0];
                float gf = acc[mi][1][r] + (float)xgc[xoff + 1 * 512 + c] + bv[1];
                float gg = acc[mi][2][r] + (float)xgc[xoff + 2 * 512 + c] + bv[2];
                float go = acc[mi][3][r] + (float)xgc[xoff + 3 * 512 + c] + bv[3];
                float cn = sigf(gf) * creg[mi][r] + sigf(gi) * tanhf(gg);
                float hn = sigf(go) * tanhf(cn);
                creg[mi][r] = cn;
                stb16(wbase + (size_t)m * 1024 + c, (bf16_t)hn);
            }
        if (s + 1 < s0 + nsteps)
            gbar(bars + (size_t)(grp * nsteps + (s - s0)) * BAR_STRIDE, 32);
    }

#pragma unroll
    for (int mi = 0; mi < 4; ++mi)
#pragma unroll
        for (int r = 0; r < 4; ++r) {
            int m = m0 + mi * 16 + quad * 4 + r;
            cst[((size_t)d * NB + m) * 512 + c] = creg[mi][r];
        }
}

// ---------------------------------------------------------------------------
// Persistent decoder: 128 blocks x 128 thr (2 waves). Group g = bi&1 (64
// blocks, batches g*64..g*64+63) — fully independent pipelines. Per step:
//   [wave-split GEMM K=1024 -> LDS combine -> poll idx_ring[t-1] -> cell +
//    epilogue (hdec 2-slot ring, hseq ring)] -> group barrier ->
//   [phase B: 1 tag/thread logits from LDS hrow, softmax/argmax/loss,
//    write idx_ring[t]]  (no second barrier).
// ---------------------------------------------------------------------------
__global__ __launch_bounds__(128) void k_dec_persist(const bf16_t* __restrict__ encb,
                                                     const bf16_t* __restrict__ whh,
                                                     const float* __restrict__ bias,
                                                     const float* __restrict__ wihT,
                                                     const float* __restrict__ out_w,
                                                     const float* __restrict__ out_b,
                                                     const int* __restrict__ tags,
                                                     bf16_t* __restrict__ hseq,
                                                     float* __restrict__ hdecR,
                                                     int* __restrict__ idxR,
                                                     unsigned* __restrict__ bars,
                                                     float* __restrict__ prob_out,
                                                     float* __restrict__ loss_out) {
    const int tid = threadIdx.x;
    const int wv = tid >> 6, lane = tid & 63;
    const int bi = blockIdx.x;
    const int g = bi & 1;
    const int l15 = lane & 15, quad = lane >> 4;
    const int m0 = g * 64;
    const int c0 = (bi >> 1) * 16;
    const int c = c0 + l15;
    const int b = (bi >> 1) + g * 64;  // phase-B batch (same m-group)

    __shared__ float paccS[64][65];
    __shared__ float hrowS[HD];
    __shared__ float logitS[TT];
    __shared__ float lseS;

    unsigned* barG = bars + (size_t)(g * (LQ + 1)) * BAR_STRIDE;

    // ---- init: hseq[0] = enc[0] (slot 1), cells = [fb, fb] (wave0 owns) ----
    float creg[4][4];
    if (wv == 0) {
#pragma unroll
        for (int mi = 0; mi < 4; ++mi)
#pragma unroll
            for (int r = 0; r < 4; ++r) {
                int m = m0 + mi * 16 + quad * 4 + r;
                creg[mi][r] = (float)encb[((size_t)1 * NB + m) * 1024 + 512 + (c & 511)];
                stb16(hseq + (size_t)m * HD + c, encb[((size_t)1 * NB + m) * 1024 + c]);
            }
    }

    // ---- hoisted constants ----
    const bf16_t* brow[4];
#pragma unroll
    for (int g4 = 0; g4 < 4; ++g4) brow[g4] = whh + (size_t)(g4 * 1024 + c0 + l15) * 1024;
    float bv[4];
#pragma unroll
    for (int g4 = 0; g4 < 4; ++g4) bv[g4] = bias[g4 * 1024 + c];
    size_t aoff[4];
#pragma unroll
    for (int mi = 0; mi < 4; ++mi) aoff[mi] = (size_t)(m0 + mi * 16 + l15) * 1024;
    const int kw = wv * 512;  // per-wave K half

    const float4* wl = (const float4*)(out_w + (size_t)tid * HD);
    const float ob = out_b[tid];
    float loss_acc = 0.0f;

    gbar(barG, 64);  // instance 0: hseq[0] ready group-wide

    for (int t = 0; t < LQ; ++t) {
        // ================= phase A: wave-split gate GEMM =================
        const bf16_t* hin = hseq + (size_t)t * (NB * HD);

        f32x4 acc[4][4] = {};
        {
            bf16x8 a0[4], b0[4], a1[4], b1[4];
            auto LD = [&](bf16x8* A, bf16x8* B, int kb) {
#pragma unroll
                for (int mi = 0; mi < 4; ++mi) A[mi] = ldf(hin + aoff[mi] + kb + quad * 8);
#pragma unroll
                for (int g4 = 0; g4 < 4; ++g4) B[g4] = ldf(brow[g4] + kb + quad * 8);
            };
            auto MM = [&](bf16x8* A, bf16x8* B) {
#pragma unroll
                for (int mi = 0; mi < 4; ++mi)
#pragma unroll
                    for (int g4 = 0; g4 < 4; ++g4)
                        acc[mi][g4] = mfma16(A[mi], B[g4], acc[mi][g4]);
            };
            LD(a0, b0, kw);
            for (int it = 0; it < 7; ++it) {
                int kb = kw + it * 64;
                LD(a1, b1, kb + 32); MM(a0, b0);
                LD(a0, b0, kb + 64); MM(a1, b1);
            }
            LD(a1, b1, kw + 480); MM(a0, b0); MM(a1, b1);
        }
        // combine wave1 partials into wave0
        if (wv == 1) {
#pragma unroll
            for (int mi = 0; mi < 4; ++mi)
#pragma unroll
                for (int g4 = 0; g4 < 4; ++g4)
#pragma unroll
                    for (int r = 0; r < 4; ++r)
                        paccS[lane][mi * 16 + g4 * 4 + r] = acc[mi][g4][r];
        }
        __syncthreads();

        if (wv == 0) {
#pragma unroll
            for (int mi = 0; mi < 4; ++mi)
#pragma unroll
                for (int g4 = 0; g4 < 4; ++g4)
#pragma unroll
                    for (int r = 0; r < 4; ++r)
                        acc[mi][g4][r] += paccS[lane][mi * 16 + g4 * 4 + r];

            // poll idx_ring[t-1] (phase B of t-1 finished long ago, ~0 wait)
            int idv = -1;
            if (t > 0) {
                const int* ir = idxR + (size_t)(t - 1) * NB;
                do {
                    idv = __hip_atomic_load(ir + m0 + lane, __ATOMIC_RELAXED,
                                            __HIP_MEMORY_SCOPE_AGENT);
                } while (idv < 0);
            }

            float* hdec = hdecR + (size_t)(t & 1) * (NB * HD);
            bf16_t* wnext = hseq + (size_t)(t + 1) * (NB * HD);
#pragma unroll
            for (int mi = 0; mi < 4; ++mi)
#pragma unroll
                for (int r = 0; r < 4; ++r) {
                    int m = m0 + mi * 16 + quad * 4 + r;
                    int id = (t > 0) ? __shfl(idv, mi * 16 + quad * 4 + r) : -1;
                    float gv[4];
#pragma unroll
                    for (int g4 = 0; g4 < 4; ++g4) {
                        float wi = (id >= 0)
                            ? wihT[(size_t)id * 4096 + g4 * 1024 + c] : 0.0f;
                        gv[g4] = acc[mi][g4][r] + bv[g4] + wi;
                    }
                    float cn = sigf(gv[1]) * creg[mi][r] + sigf(gv[0]) * tanhf(gv[2]);
                    float hn = sigf(gv[3]) * tanhf(cn);
                    creg[mi][r] = cn;
                    stf32(hdec + (size_t)m * HD + c, hn);
                    if (t + 1 < LQ)
                        stb16(wnext + (size_t)m * HD + c,
                              (bf16_t)(hn + (float)encb[((size_t)(t + 2) * NB + m) * 1024 + c]));
                }
        }
        gbar(barG + (size_t)(1 + t) * BAR_STRIDE, 64);

        // ================= phase B: logits / softmax / argmax / loss =======
        const unsigned* hsrc =
            (const unsigned*)(hdecR + (size_t)(t & 1) * (NB * HD) + (size_t)b * HD);
#pragma unroll
        for (int k = 0; k < 8; ++k) {
            unsigned v = __hip_atomic_load(hsrc + tid + k * 128, __ATOMIC_RELAXED,
                                           __HIP_MEMORY_SCOPE_AGENT);
            ((unsigned*)hrowS)[tid + k * 128] = v;
        }
        __syncthreads();

        float a = ob;
        for (int k = 0; k < HD / 4; ++k) {
            float4 h4 = ((const float4*)hrowS)[k];
            float4 x = wl[k];
            a += h4.x * x.x + h4.y * x.y + h4.z * x.z + h4.w * x.w;
        }
        logitS[tid] = a;
        __syncthreads();

        if (wv == 0) {
            float a0 = logitS[lane], a1 = logitS[lane + 64];
            float mx = fmaxf(a0, a1);
#pragma unroll
            for (int o2 = 32; o2 > 0; o2 >>= 1) mx = fmaxf(mx, __shfl_xor(mx, o2));
            float sm = __expf(a0 - mx) + __expf(a1 - mx);
#pragma unroll
            for (int o2 = 32; o2 > 0; o2 >>= 1) sm += __shfl_xor(sm, o2);
            float lse = mx + logf(sm);

            float bvv; int bix;
            if (a1 > a0) { bvv = a1; bix = lane + 64; } else { bvv = a0; bix = lane; }
#pragma unroll
            for (int o2 = 32; o2 > 0; o2 >>= 1) {
                float ov = __shfl_xor(bvv, o2);
                int oi = __shfl_xor(bix, o2);
                if (ov > bvv || (ov == bvv && oi < bix)) { bvv = ov; bix = oi; }
            }
            if (lane == 0) {
                __hip_atomic_store(idxR + (size_t)t * NB + b, bix, __ATOMIC_RELAXED,
                                   __HIP_MEMORY_SCOPE_AGENT);
                lseS = lse;
                int tg = tags[b * LQ + t];
                loss_acc += -(logitS[tg] - lse) * (1.0f / 128.0f);
            }
        }
        __syncthreads();
        prob_out[(size_t)b * (LQ * TT) + (size_t)t * TT + tid] = __expf(a - lseS);
        // no trailing barrier: next GEMM reads hseq[t+1] (pre-barrier data);
        // idx(t) consumed via polling in next epilogue.
    }
    if (tid == 0) atomicAdd(loss_out, loss_acc);
}

// ---------------------------------------------------------------------------
extern "C" void kernel_launch(void* const* d_in, const int* in_sizes, int n_in,
                              void* d_out, int out_size, void* d_ws, size_t ws_size,
                              hipStream_t stream) {
    (void)in_sizes; (void)n_in; (void)out_size;
    const int*   ids    = (const int*)d_in[0];
    const int*   tags   = (const int*)d_in[1];
    const float* embed  = (const float*)d_in[2];
    const float* e0_wih = (const float*)d_in[3];
    const float* e0_whh = (const float*)d_in[4];
    const float* e0_b   = (const float*)d_in[5];
    const float* e1_wih = (const float*)d_in[6];
    const float* e1_whh = (const float*)d_in[7];
    const float* e1_b   = (const float*)d_in[8];
    const float* d_wih  = (const float*)d_in[9];
    const float* d_whh  = (const float*)d_in[10];
    const float* d_b    = (const float*)d_in[11];
    const float* out_w  = (const float*)d_in[12];
    const float* out_b  = (const float*)d_in[13];
    float* prob = (float*)d_out;

    char* ws = (char*)d_ws;
    size_t off = 0;
    auto alloc = [&](size_t bytes) -> void* {
        void* p = ws + off;
        off += (bytes + 255) & ~(size_t)255;
        return p;
    };
    // bf16 weights (~28 MiB) + wihT (2 MiB):
    bf16_t* e0wihB = (bf16_t*)alloc((size_t)2 * 2048 * 512 * 2);
    bf16_t* e0whhB = (bf16_t*)alloc((size_t)2 * 2048 * 512 * 2);
    bf16_t* e1wihB = (bf16_t*)alloc((size_t)2 * 2048 * 1024 * 2);
    bf16_t* e1whhB = (bf16_t*)alloc((size_t)2 * 2048 * 512 * 2);
    bf16_t* dwhhB  = (bf16_t*)alloc((size_t)4096 * 1024 * 2);
    float*  wihT   = (float*)alloc((size_t)128 * 4096 * 4);
    // per-timestep state rings:
    bf16_t* h1    = (bf16_t*)alloc((size_t)(LQ + 2) * NB * 1024 * 2);  // enc0 ring
    bf16_t* encb  = (bf16_t*)alloc((size_t)(LQ + 2) * NB * 1024 * 2);  // enc1 ring
    bf16_t* hseqD = (bf16_t*)alloc((size_t)LQ * NB * HD * 2);          // decoder ring
    float*  cstE  = (float*)alloc((size_t)2 * 2 * NB * 512 * 4);
    float*  hdecR = (float*)alloc((size_t)2 * NB * HD * 4);            // 2-slot ring
    int*    idxR  = (int*)alloc((size_t)LQ * NB * 4);                  // idx ring
    // barrier sets: 2048 instances x 1 KiB = 2 MiB, pre-zeroed.
    unsigned* bars = (unsigned*)alloc((size_t)2048 * BAR_STRIDE * 4);
    size_t fixed_end = off;

    static const int ch_opts[] = {40, 32, 20, 16, 10, 8, 5, 4, 2, 1};
    int CH = 1;
    for (int i = 0; i < 10; ++i) {
        size_t need = (size_t)ch_opts[i] * NB * 4096 * 2;
        if (fixed_end + need <= ws_size) { CH = ch_opts[i]; break; }
    }
    bf16_t* xgc = (bf16_t*)alloc((size_t)CH * NB * 4096 * 2);

    // ---- one-time weight conversion / transpose ----
    auto cvt = [&](const float* s, bf16_t* d, size_t n) {
        int n4 = (int)(n / 4);
        k_cvt<<<dim3((n4 + 255) / 256), 256, 0, stream>>>(s, d, n4);
    };
    cvt(e0_wih, e0wihB, (size_t)2 * 2048 * 512);
    cvt(e0_whh, e0whhB, (size_t)2 * 2048 * 512);
    cvt(e1_wih, e1wihB, (size_t)2 * 2048 * 1024);
    cvt(e1_whh, e1whhB, (size_t)2 * 2048 * 512);
    cvt(d_whh, dwhhB, (size_t)4096 * 1024);
    k_tw<<<dim3((4096 * 128 + 255) / 256), 256, 0, stream>>>(d_wih, wihT);

    const size_t SLOT = (size_t)NB * 1024;
    hipMemsetAsync(h1, 0, SLOT * 2, stream);
    hipMemsetAsync(h1 + (size_t)(LQ + 1) * SLOT, 0, SLOT * 2, stream);
    hipMemsetAsync(encb, 0, SLOT * 2, stream);
    hipMemsetAsync(encb + (size_t)(LQ + 1) * SLOT, 0, SLOT * 2, stream);
    hipMemsetAsync(cstE, 0, (size_t)2 * 2 * NB * 512 * 4, stream);
    hipMemsetAsync(idxR, 0xFF, (size_t)LQ * NB * 4, stream);
    hipMemsetAsync(bars, 0, (size_t)2048 * BAR_STRIDE * 4, stream);
    hipMemsetAsync(prob + (size_t)NB * LQ * TT, 0, 4, stream);  // loss scalar

    // barrier instance layout: enc layer l, chunk cc -> base (l*LQ + cc*CH)*4;
    // decoder -> base 8*LQ, 2 groups x (LQ+1).
    // ---- encoder layer 0 ----
    for (int cc = 0; cc < LQ / CH; ++cc) {
        int s0 = cc * CH;
        k_xg0c<<<dim3(CH * 2, 32, 2), 64, 0, stream>>>(ids, embed, e0wihB, xgc, s0);
        k_enc_chunk<<<dim3(128), 64, 0, stream>>>(
            h1, e0whhB, e0_b, xgc, cstE,
            bars + (size_t)(cc * CH * 4) * BAR_STRIDE, s0, CH);
    }
    // ---- encoder layer 1 ----
    for (int cc = 0; cc < LQ / CH; ++cc) {
        int s0 = cc * CH;
        k_xg1c<<<dim3(CH * 2, 32, 2), 64, 0, stream>>>(h1, e1wihB, xgc, s0);
        k_enc_chunk<<<dim3(128), 64, 0, stream>>>(
            encb, e1whhB, e1_b, xgc, cstE + (size_t)2 * NB * 512,
            bars + (size_t)((LQ + cc * CH) * 4) * BAR_STRIDE, s0, CH);
    }
    // ---- decoder (one persistent launch) ----
    k_dec_persist<<<dim3(128), 128, 0, stream>>>(
        encb, dwhhB, d_b, wihT, out_w, out_b, tags, hseqD, hdecR, idxR,
        bars + (size_t)(8 * LQ) * BAR_STRIDE, prob,
        prob + (size_t)NB * LQ * TT);
}

// Round 8
// 12785.275 us; speedup vs baseline: 1.8244x; 1.2679x over previous
//
#include <hip/hip_runtime.h>

// ---------------------------------------------------------------------------
// FocusModel: embed -> bidir LSTM (E=512->HE=512) -> bidir LSTM (1024->512)
//          -> decoder LSTM (HD=1024, one-hot argmax feedback) -> softmax/loss
// R11: R10 proved the dominant per-step cost is the exposed LLC-load latency
// chain in the recurrent GEMM (halving it halved step time). Pull harder:
//   - decoder: 4-wave K-split (256 thr, K=256/wave, 8-LD chain), LDS combine;
//     phase-B logits dot split 2-way across 256 threads.
//   - encoder: 2-wave K-split (128 thr, K=256/wave), LDS combine (direct port
//     of the R10 decoder pattern); barrier groups stay 32 blocks.
//   - everything else (rings, write-through stores, relaxed distributed
//     barrier, idx-ring polling, one barrier/step) identical to R10.
// ---------------------------------------------------------------------------

typedef __bf16 bf16_t;
typedef __bf16 bf16x8 __attribute__((ext_vector_type(8)));
typedef __bf16 bf16x4 __attribute__((ext_vector_type(4)));
typedef float  f32x4  __attribute__((ext_vector_type(4)));

#define NB 128
#define LQ 160
#define EE 512
#define HE 512
#define HD 1024
#define TT 128

__device__ __forceinline__ f32x4 mfma16(bf16x8 a, bf16x8 b, f32x4 c) {
    return __builtin_amdgcn_mfma_f32_16x16x32_bf16(a, b, c, 0, 0, 0);
}
__device__ __forceinline__ bf16x8 ldf(const bf16_t* p) { return *(const bf16x8*)p; }
__device__ __forceinline__ float sigf(float x) { return 1.0f / (1.0f + __expf(-x)); }

// write-through (agent-scope) stores: visible at the coherent point.
__device__ __forceinline__ void stb16(bf16_t* p, bf16_t v) {
    union { bf16_t b; unsigned short u; } cv;
    cv.b = v;
    __hip_atomic_store((unsigned short*)p, cv.u, __ATOMIC_RELAXED,
                       __HIP_MEMORY_SCOPE_AGENT);
}
__device__ __forceinline__ void stf32(float* p, float v) {
    union { float f; unsigned u; } cv;
    cv.f = v;
    __hip_atomic_store((unsigned*)p, cv.u, __ATOMIC_RELAXED,
                       __HIP_MEMORY_SCOPE_AGENT);
}

// 8 f32 -> bf16x8 (RNE).
__device__ __forceinline__ bf16x8 cvt8(const float* p) {
    float4 f0 = ((const float4*)p)[0];
    float4 f1 = ((const float4*)p)[1];
    bf16x8 a;
    a[0] = (bf16_t)f0.x; a[1] = (bf16_t)f0.y; a[2] = (bf16_t)f0.z; a[3] = (bf16_t)f0.w;
    a[4] = (bf16_t)f1.x; a[5] = (bf16_t)f1.y; a[6] = (bf16_t)f1.z; a[7] = (bf16_t)f1.w;
    return a;
}

// ---------------------------------------------------------------------------
// Distributed group barrier (generation-free, no cache maintenance).
// ---------------------------------------------------------------------------
#define BAR_STRIDE 256  // u32s per instance (16 lines x 16 u32 = 1 KiB)
__device__ __forceinline__ void gbar(unsigned* __restrict__ lines, unsigned nblk) {
    asm volatile("s_waitcnt vmcnt(0)" ::: "memory");
    __syncthreads();
    if (threadIdx.x == 0)
        __hip_atomic_fetch_add(lines + ((blockIdx.x >> 1) & 15) * 16, 1u,
                               __ATOMIC_RELAXED, __HIP_MEMORY_SCOPE_AGENT);
    if (threadIdx.x < 16) {
        for (;;) {
            unsigned s = __hip_atomic_load(lines + threadIdx.x * 16,
                                           __ATOMIC_RELAXED,
                                           __HIP_MEMORY_SCOPE_AGENT);
            s += __shfl_xor(s, 1);
            s += __shfl_xor(s, 2);
            s += __shfl_xor(s, 4);
            s += __shfl_xor(s, 8);
            if (s >= nblk) break;
            __builtin_amdgcn_s_sleep(2);
        }
    }
    __syncthreads();
}

// f32 -> bf16 bulk convert.
__global__ __launch_bounds__(256) void k_cvt(const float* __restrict__ src,
                                             bf16_t* __restrict__ dst, int n4) {
    int i = blockIdx.x * 256 + threadIdx.x;
    if (i < n4) {
        float4 v = ((const float4*)src)[i];
        bf16x4 o;
        o[0] = (bf16_t)v.x; o[1] = (bf16_t)v.y; o[2] = (bf16_t)v.z; o[3] = (bf16_t)v.w;
        ((bf16x4*)dst)[i] = o;
    }
}

// dec_wih [4096][128] -> wihT [128][4096] (f32), for coalesced id-gather.
__global__ __launch_bounds__(256) void k_tw(const float* __restrict__ w,
                                            float* __restrict__ wt) {
    int i = blockIdx.x * 256 + threadIdx.x;
    if (i < 4096 * 128) {
        int r = i >> 7, c2 = i & 127;
        wt[(size_t)c2 * 4096 + r] = w[i];
    }
}

// ---------------------------------------------------------------------------
// Chunked input projection, layer 0 (embed gather fused, f32->bf16 in-reg).
// ---------------------------------------------------------------------------
__global__ __launch_bounds__(64) void k_xg0c(const int* __restrict__ ids,
                                             const float* __restrict__ embed,
                                             const bf16_t* __restrict__ wih,
                                             bf16_t* __restrict__ xgc,
                                             int s0) {
    const int lane = threadIdx.x;
    const int l15 = lane & 15, quad = lane >> 4;
    const int m0 = blockIdx.x * 64;
    const int n0 = blockIdx.y * 64;
    const int d  = blockIdx.z;
    const bf16_t* Wd = wih + (size_t)d * 2048 * 512;

    const float* arow[4];
#pragma unroll
    for (int mi = 0; mi < 4; ++mi) {
        int m = m0 + mi * 16 + l15;
        int b = m & 127, s = s0 + (m >> 7);
        int t = d ? (LQ - 1 - s) : s;
        int id = ids[b * LQ + t];
        arow[mi] = embed + (size_t)id * EE;
    }
    const bf16_t* brow[4];
#pragma unroll
    for (int ni = 0; ni < 4; ++ni) brow[ni] = Wd + (size_t)(n0 + ni * 16 + l15) * 512;

    f32x4 acc[4][4] = {};
    for (int kb = 0; kb < 512; kb += 32) {
        bf16x8 af[4], bfr[4];
#pragma unroll
        for (int mi = 0; mi < 4; ++mi) af[mi] = cvt8(arow[mi] + kb + quad * 8);
#pragma unroll
        for (int ni = 0; ni < 4; ++ni) bfr[ni] = ldf(brow[ni] + kb + quad * 8);
#pragma unroll
        for (int mi = 0; mi < 4; ++mi)
#pragma unroll
            for (int ni = 0; ni < 4; ++ni)
                acc[mi][ni] = mfma16(af[mi], bfr[ni], acc[mi][ni]);
    }
#pragma unroll
    for (int mi = 0; mi < 4; ++mi)
#pragma unroll
        for (int ni = 0; ni < 4; ++ni)
#pragma unroll
            for (int r = 0; r < 4; ++r) {
                int m = m0 + mi * 16 + quad * 4 + r;
                int n = n0 + ni * 16 + l15;
                xgc[(size_t)m * 4096 + d * 2048 + n] = (bf16_t)acc[mi][ni][r];
            }
}

// Chunked input projection, layer 1: A-row = h1ring[1+t][b] (1024 wide).
__global__ __launch_bounds__(64) void k_xg1c(const bf16_t* __restrict__ h1,
                                             const bf16_t* __restrict__ wih,
                                             bf16_t* __restrict__ xgc,
                                             int s0) {
    const int lane = threadIdx.x;
    const int l15 = lane & 15, quad = lane >> 4;
    const int m0 = blockIdx.x * 64;
    const int n0 = blockIdx.y * 64;
    const int d  = blockIdx.z;
    const bf16_t* Wd = wih + (size_t)d * 2048 * 1024;

    const bf16_t* arow[4];
#pragma unroll
    for (int mi = 0; mi < 4; ++mi) {
        int m = m0 + mi * 16 + l15;
        int b = m & 127, s = s0 + (m >> 7);
        int t = d ? (LQ - 1 - s) : s;
        arow[mi] = h1 + ((size_t)(1 + t) * NB + b) * 1024;
    }
    const bf16_t* brow[4];
#pragma unroll
    for (int ni = 0; ni < 4; ++ni) brow[ni] = Wd + (size_t)(n0 + ni * 16 + l15) * 1024;

    f32x4 acc[4][4] = {};
    for (int kb = 0; kb < 1024; kb += 32) {
        bf16x8 af[4], bfr[4];
#pragma unroll
        for (int mi = 0; mi < 4; ++mi) af[mi] = ldf(arow[mi] + kb + quad * 8);
#pragma unroll
        for (int ni = 0; ni < 4; ++ni) bfr[ni] = ldf(brow[ni] + kb + quad * 8);
#pragma unroll
        for (int mi = 0; mi < 4; ++mi)
#pragma unroll
            for (int ni = 0; ni < 4; ++ni)
                acc[mi][ni] = mfma16(af[mi], bfr[ni], acc[mi][ni]);
    }
#pragma unroll
    for (int mi = 0; mi < 4; ++mi)
#pragma unroll
        for (int ni = 0; ni < 4; ++ni)
#pragma unroll
            for (int r = 0; r < 4; ++r) {
                int m = m0 + mi * 16 + quad * 4 + r;
                int n = n0 + ni * 16 + l15;
                xgc[(size_t)m * 4096 + d * 2048 + n] = (bf16_t)acc[mi][ni][r];
            }
}

// ---------------------------------------------------------------------------
// Persistent encoder chunk. 128 blocks x 128 thr (2 waves, K=256/wave).
// Block bi -> m-block (bi&1), col-block ((bi>>1)&31), dir (bi>>6).
// Wave1 partials combined into wave0 via LDS; wave0 owns cells + stores.
// Barrier group = (m-block, dir): 32 blocks.
// ---------------------------------------------------------------------------
__global__ __launch_bounds__(128) void k_enc_chunk(bf16_t* __restrict__ hring,
                                                   const bf16_t* __restrict__ whh,
                                                   const float* __restrict__ bias,
                                                   const bf16_t* __restrict__ xgc,
                                                   float* __restrict__ cst,
                                                   unsigned* __restrict__ bars,
                                                   int s0, int nsteps) {
    const int tid = threadIdx.x;
    const int wv = tid >> 6, lane = tid & 63;
    const int l15 = lane & 15, quad = lane >> 4;
    const int bi = blockIdx.x;
    const int m0 = (bi & 1) * 64;
    const int c0 = ((bi >> 1) & 31) * 16;
    const int d  = bi >> 6;
    const int grp = (bi & 1) | ((bi >> 6) << 1);
    const int kw = wv * 256;  // per-wave K half

    __shared__ float paccS[64][65];

    const bf16_t* Wd = whh + (size_t)d * 2048 * 512;
    const bf16_t* brow[4];
#pragma unroll
    for (int g4 = 0; g4 < 4; ++g4) brow[g4] = Wd + (size_t)(g4 * 512 + c0 + l15) * 512;
    const int c = c0 + l15;
    float bv[4];
#pragma unroll
    for (int g4 = 0; g4 < 4; ++g4) bv[g4] = bias[d * 2048 + g4 * 512 + c];
    size_t aoff[4];
#pragma unroll
    for (int mi = 0; mi < 4; ++mi) aoff[mi] = (size_t)(m0 + mi * 16 + l15) * 1024;

    float creg[4][4];
    if (wv == 0) {
#pragma unroll
        for (int mi = 0; mi < 4; ++mi)
#pragma unroll
            for (int r = 0; r < 4; ++r) {
                int m = m0 + mi * 16 + quad * 4 + r;
                creg[mi][r] = cst[((size_t)d * NB + m) * 512 + c];
            }
    }

    for (int s = s0; s < s0 + nsteps; ++s) {
        const int t     = d ? (LQ - 1 - s) : s;
        const int tprev = d ? (LQ - s)     : (s - 1);
        const bf16_t* abase = hring + ((size_t)(1 + tprev) * NB) * 1024 + (size_t)d * 512;

        f32x4 acc[4][4] = {};
        {
            bf16x8 a0[4], b0[4], a1[4], b1[4];
            auto LD = [&](bf16x8* A, bf16x8* B, int kb) {
#pragma unroll
                for (int mi = 0; mi < 4; ++mi) A[mi] = ldf(abase + aoff[mi] + kb + quad * 8);
#pragma unroll
                for (int g4 = 0; g4 < 4; ++g4) B[g4] = ldf(brow[g4] + kb + quad * 8);
            };
            auto MM = [&](bf16x8* A, bf16x8* B) {
#pragma unroll
                for (int mi = 0; mi < 4; ++mi)
#pragma unroll
                    for (int g4 = 0; g4 < 4; ++g4)
                        acc[mi][g4] = mfma16(A[mi], B[g4], acc[mi][g4]);
            };
            LD(a0, b0, kw);
            for (int it = 0; it < 3; ++it) {
                int kb = kw + it * 64;
                LD(a1, b1, kb + 32); MM(a0, b0);
                LD(a0, b0, kb + 64); MM(a1, b1);
            }
            LD(a1, b1, kw + 224); MM(a0, b0); MM(a1, b1);
        }
        if (wv == 1) {
#pragma unroll
            for (int mi = 0; mi < 4; ++mi)
#pragma unroll
                for (int g4 = 0; g4 < 4; ++g4)
#pragma unroll
                    for (int r = 0; r < 4; ++r)
                        paccS[lane][mi * 16 + g4 * 4 + r] = acc[mi][g4][r];
        }
        __syncthreads();

        if (wv == 0) {
            bf16_t* wbase = hring + ((size_t)(1 + t) * NB) * 1024 + (size_t)d * 512;
#pragma unroll
            for (int mi = 0; mi < 4; ++mi)
#pragma unroll
                for (int r = 0; r < 4; ++r) {
                    int m = m0 + mi * 16 + quad * 4 + r;
                    size_t xoff = ((size_t)(s - s0) * NB + m) * 4096 + (size_t)d * 2048;
                    float p0 = paccS[lane][mi * 16 + 0 * 4 + r];
                    float p1 = paccS[lane][mi * 16 + 1 * 4 + r];
                    float p2 = paccS[lane][mi * 16 + 2 * 4 + r];
                    float p3 = paccS[lane][mi * 16 + 3 * 4 + r];
                    float gi = acc[mi][0][r] + p0 + (float)xgc[xoff + 0 * 512 + c] + bv[0];
                    float gf = acc[mi][1][r] + p1 + (float)xgc[xoff + 1 * 512 + c] + bv[1];
                    float gg = acc[mi][2][r] + p2 + (float)xgc[xoff + 2 * 512 + c] + bv[2];
                    float go = acc[mi][3][r] + p3 + (float)xgc[xoff + 3 * 512 + c] + bv[3];
                    float cn = sigf(gf) * creg[mi][r] + sigf(gi) * tanhf(gg);
                    float hn = sigf(go) * tanhf(cn);
                    creg[mi][r] = cn;
                    stb16(wbase + (size_t)m * 1024 + c, (bf16_t)hn);
                }
        }
        if (s + 1 < s0 + nsteps)
            gbar(bars + (size_t)(grp * nsteps + (s - s0)) * BAR_STRIDE, 32);
        else
            __syncthreads();  // protect paccS before kernel end (noop mostly)
    }

    if (wv == 0) {
#pragma unroll
        for (int mi = 0; mi < 4; ++mi)
#pragma unroll
            for (int r = 0; r < 4; ++r) {
                int m = m0 + mi * 16 + quad * 4 + r;
                cst[((size_t)d * NB + m) * 512 + c] = creg[mi][r];
            }
    }
}

// ---------------------------------------------------------------------------
// Persistent decoder: 128 blocks x 256 thr (4 waves, K=256/wave). Group
// g = bi&1 (64 blocks, batches g*64..); per step:
//   [4-wave K-split GEMM -> LDS combine -> wave0: poll idx_ring[t-1], cell,
//    epilogue] -> group barrier -> [phase B: 2-way-split logits dot (tag =
//    tid&127, K-half = tid>>7), wave0 softmax/argmax/loss, idx_ring[t]].
// ---------------------------------------------------------------------------
__global__ __launch_bounds__(256) void k_dec_persist(const bf16_t* __restrict__ encb,
                                                     const bf16_t* __restrict__ whh,
                                                     const float* __restrict__ bias,
                                                     const float* __restrict__ wihT,
                                                     const float* __restrict__ out_w,
                                                     const float* __restrict__ out_b,
                                                     const int* __restrict__ tags,
                                                     bf16_t* __restrict__ hseq,
                                                     float* __restrict__ hdecR,
                                                     int* __restrict__ idxR,
                                                     unsigned* __restrict__ bars,
                                                     float* __restrict__ prob_out,
                                                     float* __restrict__ loss_out) {
    const int tid = threadIdx.x;
    const int wv = tid >> 6, lane = tid & 63;
    const int bi = blockIdx.x;
    const int g = bi & 1;
    const int l15 = lane & 15, quad = lane >> 4;
    const int m0 = g * 64;
    const int c0 = (bi >> 1) * 16;
    const int c = c0 + l15;
    const int b = (bi >> 1) + g * 64;  // phase-B batch (same m-group)
    const int kw = wv * 256;           // per-wave K quarter

    __shared__ float paccS[3][64][65];
    __shared__ float hrowS[HD];
    __shared__ float plS[256];
    __shared__ float logitS[TT];
    __shared__ float lseS;

    unsigned* barG = bars + (size_t)(g * (LQ + 1)) * BAR_STRIDE;

    // ---- init: hseq[0] = enc[0] (slot 1), cells = [fb, fb] (wave0 owns) ----
    float creg[4][4];
    if (wv == 0) {
#pragma unroll
        for (int mi = 0; mi < 4; ++mi)
#pragma unroll
            for (int r = 0; r < 4; ++r) {
                int m = m0 + mi * 16 + quad * 4 + r;
                creg[mi][r] = (float)encb[((size_t)1 * NB + m) * 1024 + 512 + (c & 511)];
                stb16(hseq + (size_t)m * HD + c, encb[((size_t)1 * NB + m) * 1024 + c]);
            }
    }

    // ---- hoisted constants ----
    const bf16_t* brow[4];
#pragma unroll
    for (int g4 = 0; g4 < 4; ++g4) brow[g4] = whh + (size_t)(g4 * 1024 + c0 + l15) * 1024;
    float bv[4];
#pragma unroll
    for (int g4 = 0; g4 < 4; ++g4) bv[g4] = bias[g4 * 1024 + c];
    size_t aoff[4];
#pragma unroll
    for (int mi = 0; mi < 4; ++mi) aoff[mi] = (size_t)(m0 + mi * 16 + l15) * 1024;

    const int tg2 = tid & 127, khalf = tid >> 7;
    const float4* wl = (const float4*)(out_w + (size_t)tg2 * HD + khalf * 512);
    const float ob = out_b[tg2];
    float loss_acc = 0.0f;

    gbar(barG, 64);  // instance 0: hseq[0] ready group-wide

    for (int t = 0; t < LQ; ++t) {
        // ================= phase A: 4-wave K-split gate GEMM ================
        const bf16_t* hin = hseq + (size_t)t * (NB * HD);

        f32x4 acc[4][4] = {};
        {
            bf16x8 a0[4], b0[4], a1[4], b1[4];
            auto LD = [&](bf16x8* A, bf16x8* B, int kb) {
#pragma unroll
                for (int mi = 0; mi < 4; ++mi) A[mi] = ldf(hin + aoff[mi] + kb + quad * 8);
#pragma unroll
                for (int g4 = 0; g4 < 4; ++g4) B[g4] = ldf(brow[g4] + kb + quad * 8);
            };
            auto MM = [&](bf16x8* A, bf16x8* B) {
#pragma unroll
                for (int mi = 0; mi < 4; ++mi)
#pragma unroll
                    for (int g4 = 0; g4 < 4; ++g4)
                        acc[mi][g4] = mfma16(A[mi], B[g4], acc[mi][g4]);
            };
            LD(a0, b0, kw);
            for (int it = 0; it < 3; ++it) {
                int kb = kw + it * 64;
                LD(a1, b1, kb + 32); MM(a0, b0);
                LD(a0, b0, kb + 64); MM(a1, b1);
            }
            LD(a1, b1, kw + 224); MM(a0, b0); MM(a1, b1);
        }
        if (wv >= 1) {
#pragma unroll
            for (int mi = 0; mi < 4; ++mi)
#pragma unroll
                for (int g4 = 0; g4 < 4; ++g4)
#pragma unroll
                    for (int r = 0; r < 4; ++r)
                        paccS[wv - 1][lane][mi * 16 + g4 * 4 + r] = acc[mi][g4][r];
        }
        __syncthreads();

        if (wv == 0) {
#pragma unroll
            for (int mi = 0; mi < 4; ++mi)
#pragma unroll
                for (int g4 = 0; g4 < 4; ++g4)
#pragma unroll
                    for (int r = 0; r < 4; ++r)
                        acc[mi][g4][r] += paccS[0][lane][mi * 16 + g4 * 4 + r]
                                        + paccS[1][lane][mi * 16 + g4 * 4 + r]
                                        + paccS[2][lane][mi * 16 + g4 * 4 + r];

            // poll idx_ring[t-1] (phase B of t-1 finished long ago, ~0 wait)
            int idv = -1;
            if (t > 0) {
                const int* ir = idxR + (size_t)(t - 1) * NB;
                do {
                    idv = __hip_atomic_load(ir + m0 + lane, __ATOMIC_RELAXED,
                                            __HIP_MEMORY_SCOPE_AGENT);
                } while (idv < 0);
            }

            float* hdec = hdecR + (size_t)(t & 1) * (NB * HD);
            bf16_t* wnext = hseq + (size_t)(t + 1) * (NB * HD);
#pragma unroll
            for (int mi = 0; mi < 4; ++mi)
#pragma unroll
                for (int r = 0; r < 4; ++r) {
                    int m = m0 + mi * 16 + quad * 4 + r;
                    int id = (t > 0) ? __shfl(idv, mi * 16 + quad * 4 + r) : -1;
                    float gv[4];
#pragma unroll
                    for (int g4 = 0; g4 < 4; ++g4) {
                        float wi = (id >= 0)
                            ? wihT[(size_t)id * 4096 + g4 * 1024 + c] : 0.0f;
                        gv[g4] = acc[mi][g4][r] + bv[g4] + wi;
                    }
                    float cn = sigf(gv[1]) * creg[mi][r] + sigf(gv[0]) * tanhf(gv[2]);
                    float hn = sigf(gv[3]) * tanhf(cn);
                    creg[mi][r] = cn;
                    stf32(hdec + (size_t)m * HD + c, hn);
                    if (t + 1 < LQ)
                        stb16(wnext + (size_t)m * HD + c,
                              (bf16_t)(hn + (float)encb[((size_t)(t + 2) * NB + m) * 1024 + c]));
                }
        }
        gbar(barG + (size_t)(1 + t) * BAR_STRIDE, 64);

        // ================= phase B: logits / softmax / argmax / loss =======
        const unsigned* hsrc =
            (const unsigned*)(hdecR + (size_t)(t & 1) * (NB * HD) + (size_t)b * HD);
#pragma unroll
        for (int k = 0; k < 4; ++k) {
            unsigned v = __hip_atomic_load(hsrc + tid + k * 256, __ATOMIC_RELAXED,
                                           __HIP_MEMORY_SCOPE_AGENT);
            ((unsigned*)hrowS)[tid + k * 256] = v;
        }
        __syncthreads();

        {
            const float4* hh = (const float4*)(hrowS + khalf * 512);
            float a = 0.0f;
            for (int k = 0; k < 128; ++k) {
                float4 h4 = hh[k];
                float4 x = wl[k];
                a += h4.x * x.x + h4.y * x.y + h4.z * x.z + h4.w * x.w;
            }
            plS[tid] = a;
        }
        __syncthreads();
        if (tid < 128) logitS[tid] = plS[tid] + plS[tid + 128] + ob;
        __syncthreads();

        if (wv == 0) {
            float a0 = logitS[lane], a1 = logitS[lane + 64];
            float mx = fmaxf(a0, a1);
#pragma unroll
            for (int o2 = 32; o2 > 0; o2 >>= 1) mx = fmaxf(mx, __shfl_xor(mx, o2));
            float sm = __expf(a0 - mx) + __expf(a1 - mx);
#pragma unroll
            for (int o2 = 32; o2 > 0; o2 >>= 1) sm += __shfl_xor(sm, o2);
            float lse = mx + logf(sm);

            float bvv; int bix;
            if (a1 > a0) { bvv = a1; bix = lane + 64; } else { bvv = a0; bix = lane; }
#pragma unroll
            for (int o2 = 32; o2 > 0; o2 >>= 1) {
                float ov = __shfl_xor(bvv, o2);
                int oi = __shfl_xor(bix, o2);
                if (ov > bvv || (ov == bvv && oi < bix)) { bvv = ov; bix = oi; }
            }
            if (lane == 0) {
                __hip_atomic_store(idxR + (size_t)t * NB + b, bix, __ATOMIC_RELAXED,
                                   __HIP_MEMORY_SCOPE_AGENT);
                lseS = lse;
                int tg = tags[b * LQ + t];
                loss_acc += -(logitS[tg] - lse) * (1.0f / 128.0f);
            }
        }
        __syncthreads();
        if (tid < 128)
            prob_out[(size_t)b * (LQ * TT) + (size_t)t * TT + tid] =
                __expf(logitS[tid] - lseS);
        __syncthreads();  // protect logitS/hrowS reuse next iteration
    }
    if (tid == 0) atomicAdd(loss_out, loss_acc);
}

// ---------------------------------------------------------------------------
extern "C" void kernel_launch(void* const* d_in, const int* in_sizes, int n_in,
                              void* d_out, int out_size, void* d_ws, size_t ws_size,
                              hipStream_t stream) {
    (void)in_sizes; (void)n_in; (void)out_size;
    const int*   ids    = (const int*)d_in[0];
    const int*   tags   = (const int*)d_in[1];
    const float* embed  = (const float*)d_in[2];
    const float* e0_wih = (const float*)d_in[3];
    const float* e0_whh = (const float*)d_in[4];
    const float* e0_b   = (const float*)d_in[5];
    const float* e1_wih = (const float*)d_in[6];
    const float* e1_whh = (const float*)d_in[7];
    const float* e1_b   = (const float*)d_in[8];
    const float* d_wih  = (const float*)d_in[9];
    const float* d_whh  = (const float*)d_in[10];
    const float* d_b    = (const float*)d_in[11];
    const float* out_w  = (const float*)d_in[12];
    const float* out_b  = (const float*)d_in[13];
    float* prob = (float*)d_out;

    char* ws = (char*)d_ws;
    size_t off = 0;
    auto alloc = [&](size_t bytes) -> void* {
        void* p = ws + off;
        off += (bytes + 255) & ~(size_t)255;
        return p;
    };
    // bf16 weights (~28 MiB) + wihT (2 MiB):
    bf16_t* e0wihB = (bf16_t*)alloc((size_t)2 * 2048 * 512 * 2);
    bf16_t* e0whhB = (bf16_t*)alloc((size_t)2 * 2048 * 512 * 2);
    bf16_t* e1wihB = (bf16_t*)alloc((size_t)2 * 2048 * 1024 * 2);
    bf16_t* e1whhB = (bf16_t*)alloc((size_t)2 * 2048 * 512 * 2);
    bf16_t* dwhhB  = (bf16_t*)alloc((size_t)4096 * 1024 * 2);
    float*  wihT   = (float*)alloc((size_t)128 * 4096 * 4);
    // per-timestep state rings:
    bf16_t* h1    = (bf16_t*)alloc((size_t)(LQ + 2) * NB * 1024 * 2);  // enc0 ring
    bf16_t* encb  = (bf16_t*)alloc((size_t)(LQ + 2) * NB * 1024 * 2);  // enc1 ring
    bf16_t* hseqD = (bf16_t*)alloc((size_t)LQ * NB * HD * 2);          // decoder ring
    float*  cstE  = (float*)alloc((size_t)2 * 2 * NB * 512 * 4);
    float*  hdecR = (float*)alloc((size_t)2 * NB * HD * 4);            // 2-slot ring
    int*    idxR  = (int*)alloc((size_t)LQ * NB * 4);                  // idx ring
    // barrier sets: 2048 instances x 1 KiB = 2 MiB, pre-zeroed.
    unsigned* bars = (unsigned*)alloc((size_t)2048 * BAR_STRIDE * 4);
    size_t fixed_end = off;

    static const int ch_opts[] = {40, 32, 20, 16, 10, 8, 5, 4, 2, 1};
    int CH = 1;
    for (int i = 0; i < 10; ++i) {
        size_t need = (size_t)ch_opts[i] * NB * 4096 * 2;
        if (fixed_end + need <= ws_size) { CH = ch_opts[i]; break; }
    }
    bf16_t* xgc = (bf16_t*)alloc((size_t)CH * NB * 4096 * 2);

    // ---- one-time weight conversion / transpose ----
    auto cvt = [&](const float* s, bf16_t* d, size_t n) {
        int n4 = (int)(n / 4);
        k_cvt<<<dim3((n4 + 255) / 256), 256, 0, stream>>>(s, d, n4);
    };
    cvt(e0_wih, e0wihB, (size_t)2 * 2048 * 512);
    cvt(e0_whh, e0whhB, (size_t)2 * 2048 * 512);
    cvt(e1_wih, e1wihB, (size_t)2 * 2048 * 1024);
    cvt(e1_whh, e1whhB, (size_t)2 * 2048 * 512);
    cvt(d_whh, dwhhB, (size_t)4096 * 1024);
    k_tw<<<dim3((4096 * 128 + 255) / 256), 256, 0, stream>>>(d_wih, wihT);

    const size_t SLOT = (size_t)NB * 1024;
    hipMemsetAsync(h1, 0, SLOT * 2, stream);
    hipMemsetAsync(h1 + (size_t)(LQ + 1) * SLOT, 0, SLOT * 2, stream);
    hipMemsetAsync(encb, 0, SLOT * 2, stream);
    hipMemsetAsync(encb + (size_t)(LQ + 1) * SLOT, 0, SLOT * 2, stream);
    hipMemsetAsync(cstE, 0, (size_t)2 * 2 * NB * 512 * 4, stream);
    hipMemsetAsync(idxR, 0xFF, (size_t)LQ * NB * 4, stream);
    hipMemsetAsync(bars, 0, (size_t)2048 * BAR_STRIDE * 4, stream);
    hipMemsetAsync(prob + (size_t)NB * LQ * TT, 0, 4, stream);  // loss scalar

    // barrier layout: enc layer l, chunk cc -> base (l*LQ + cc*CH)*4;
    // decoder -> base 8*LQ, 2 groups x (LQ+1).
    // ---- encoder layer 0 ----
    for (int cc = 0; cc < LQ / CH; ++cc) {
        int s0 = cc * CH;
        k_xg0c<<<dim3(CH * 2, 32, 2), 64, 0, stream>>>(ids, embed, e0wihB, xgc, s0);
        k_enc_chunk<<<dim3(128), 128, 0, stream>>>(
            h1, e0whhB, e0_b, xgc, cstE,
            bars + (size_t)(cc * CH * 4) * BAR_STRIDE, s0, CH);
    }
    // ---- encoder layer 1 ----
    for (int cc = 0; cc < LQ / CH; ++cc) {
        int s0 = cc * CH;
        k_xg1c<<<dim3(CH * 2, 32, 2), 64, 0, stream>>>(h1, e1wihB, xgc, s0);
        k_enc_chunk<<<dim3(128), 128, 0, stream>>>(
            encb, e1whhB, e1_b, xgc, cstE + (size_t)2 * NB * 512,
            bars + (size_t)((LQ + cc * CH) * 4) * BAR_STRIDE, s0, CH);
    }
    // ---- decoder (one persistent launch) ----
    k_dec_persist<<<dim3(128), 256, 0, stream>>>(
        encb, dwhhB, d_b, wihT, out_w, out_b, tags, hseqD, hdecR, idxR,
        bars + (size_t)(8 * LQ) * BAR_STRIDE, prob,
        prob + (size_t)NB * LQ * TT);
}